// Round 5
// baseline (3552.784 us; speedup 1.0000x reference)
//
#include <hip/hip_runtime.h>
#include <hip/hip_bf16.h>
#include <math.h>

#define H_   224
#define W_   224
#define HWsz 50176      // 224*224
#define Cch  128

// Kernel A: out tile 8x16, halo 2 -> 12x20
#define TAH 8
#define TAW 16
#define HAH 12
#define HAW 20
#define NHALO_A (HAH*HAW)   // 240

// Kernel B: patch 8 rows x 16 cols
#define PBH 8
#define PBW 16
#define GPITCH 136          // g_s row pitch in bf16 units (272 B)

typedef __bf16 bf16x8 __attribute__((ext_vector_type(8)));
typedef float  f32x4  __attribute__((ext_vector_type(4)));

__device__ __forceinline__ float bf2f(__hip_bfloat16 v) { return __bfloat162float(v); }
__device__ __forceinline__ __hip_bfloat16 f2bf(float v) { return __float2bfloat16(v); }
__device__ __forceinline__ float ubf2f(unsigned short u) {
    unsigned x = ((unsigned)u) << 16; return __int_as_float((int)x);
}
__device__ __forceinline__ unsigned short f2ubf(float f) {
    __hip_bfloat16 h = __float2bfloat16(f);
    return *reinterpret_cast<unsigned short*>(&h);
}
__device__ __forceinline__ float gelu_exact(float x) {
    return 0.5f * x * (1.0f + erff(x * 0.70710678118654752440f));
}

// =====================================================================
// prep: transpose ldw depthwise weights to dwT[tap][c]
// =====================================================================
__global__ __launch_bounds__(256)
void prep(const float* __restrict__ ldww, float* __restrict__ dwT)
{
    const int i = blockIdx.x * 256 + threadIdx.x;
    if (i < 9 * Cch) {
        const int t = i >> 7, c = i & 127;
        dwT[i] = ldww[c * 9 + t];
    }
}

// =====================================================================
// ln_stats: per-pixel LN1 statistics (mu, 1/sigma), coalesced
// =====================================================================
__global__ __launch_bounds__(256)
void ln_stats(const float* __restrict__ x, float2* __restrict__ st)
{
    const int sp = blockIdx.x * 256 + threadIdx.x;
    const int b  = blockIdx.y;
    const float* xp = x + (size_t)b * Cch * HWsz + sp;
    float s = 0.f, ss = 0.f;
    #pragma unroll 8
    for (int c = 0; c < Cch; ++c) {
        float v = xp[(size_t)c * HWsz];
        s += v; ss += v * v;
    }
    const float mu  = s * (1.0f / 128.0f);
    const float var = ss * (1.0f / 128.0f) - mu * mu;
    st[(size_t)b * HWsz + sp] = make_float2(mu, rsqrtf(var + 1e-6f));
}

// =====================================================================
// Kernel A: LN1 -> 4 shift branches + c5 -> shuffle -> z (bf16 NHWC)
// + LN2 stats
// =====================================================================
__global__ __launch_bounds__(256, 2)
void kernelA(const float* __restrict__ x, const float2* __restrict__ st1,
             const float* __restrict__ n1w, const float* __restrict__ n1b,
             const float* __restrict__ c5w, const float* __restrict__ c5b,
             const float* __restrict__ s1dw, const float* __restrict__ s1db,
             const float* __restrict__ s1pw, const float* __restrict__ s1pb,
             const float* __restrict__ s2dw, const float* __restrict__ s2db,
             const float* __restrict__ s2pw, const float* __restrict__ s2pb,
             const float* __restrict__ s3dw, const float* __restrict__ s3db,
             const float* __restrict__ s3pw, const float* __restrict__ s3pb,
             const float* __restrict__ s4dw, const float* __restrict__ s4db,
             const float* __restrict__ s4pw, const float* __restrict__ s4pb,
             unsigned int* __restrict__ zout, float2* __restrict__ st2)
{
    __shared__ __hip_bfloat16 y_s[Cch * NHALO_A];          // 61,440 B
    __shared__ float red_s[TAH * TAW], red_ss[TAH * TAW];  // 1 KB

    const int tid = threadIdx.x;
    const int b   = blockIdx.z;
    const int h0  = blockIdx.y * TAH;
    const int w0  = blockIdx.x * TAW;

    // ---------- Phase 1: single-pass LN1 into y_s ----------
    if (tid < NHALO_A) {
        const int ph = tid / HAW, pw = tid - ph * HAW;
        const int gy = h0 - 2 + ph, gx = w0 - 2 + pw;
        if (gy >= 0 && gy < H_ && gx >= 0 && gx < W_) {
            const float2 st = st1[(size_t)b * HWsz + gy * W_ + gx];
            const float* xp = x + (size_t)b * Cch * HWsz + (size_t)gy * W_ + gx;
            #pragma unroll 8
            for (int c = 0; c < Cch; ++c) {
                float v = xp[(size_t)c * HWsz];
                y_s[c * NHALO_A + tid] = f2bf((v - st.x) * st.y * n1w[c] + n1b[c]);
            }
        } else {
            for (int c = 0; c < Cch; ++c) y_s[c * NHALO_A + tid] = f2bf(0.f);
        }
    }
    __syncthreads();

    // ---------- Phase 2: (pixel x chunk-half), wave-uniform half ----------
    const int lane = tid & 63;
    const int wv   = tid >> 6;
    const int half = wv >> 1;
    const int p    = ((wv & 1) << 6) | lane;   // 0..127
    const int py   = p >> 4, px = p & 15;
    const int gh   = h0 + py, gw = w0 + px;

    bool rowOK[3], colOK[3];
    #pragma unroll
    for (int t = 0; t < 3; ++t) {
        rowOK[t] = (gh - 1 + t >= 0) && (gh - 1 + t < H_);
        colOK[t] = (gw - 1 + t >= 0) && (gw - 1 + t < W_);
    }

    float ov[2][32];

    #pragma unroll
    for (int kk = 0; kk < 2; ++kk) {
        const int k = half * 2 + kk;
        const float* dwW = (k == 0) ? s1dw : (k == 1) ? s2dw : (k == 2) ? s3dw : s4dw;
        const float* dwB = (k == 0) ? s1db : (k == 1) ? s2db : (k == 2) ? s3db : s4db;
        const float* pwW = (k == 0) ? s1pw : (k == 1) ? s2pw : (k == 2) ? s3pw : s4pw;
        const float* pwB = (k == 0) ? s1pb : (k == 1) ? s2pb : (k == 2) ? s3pb : s4pb;
        const int shh   = (k == 0) ? 1 : (k == 1) ? -1 : (k == 2) ? -1 : 1;
        const int shw   = (k == 0) ? 1 : (k == 1) ?  1 : (k == 2) ? -1 : -1;
        const int obase = (k == 0) ? 64 : (k == 1) ? 0 : (k == 2) ? 96 : 32;

        const int rb = py + 1 - shh;
        const int cb = px + 1 - shw;

        float G[32];
        #pragma unroll
        for (int i = 0; i < 32; ++i) {
            const __hip_bfloat16* yc = y_s + (32 * k + i) * NHALO_A;
            float a = dwB[i];
            #pragma unroll
            for (int t3 = 0; t3 < 3; ++t3)
                #pragma unroll
                for (int t4 = 0; t4 < 3; ++t4) {
                    float v = (rowOK[t3] && colOK[t4])
                            ? bf2f(yc[(rb + t3) * HAW + (cb + t4)]) : 0.f;
                    a += dwW[i * 9 + t3 * 3 + t4] * v;
                }
            G[i] = gelu_exact(a);
        }

        #pragma unroll
        for (int o = 0; o < 32; ++o) {
            const int c = obase + o;
            float a = pwB[o];
            #pragma unroll
            for (int i = 0; i < 32; ++i)
                a += pwW[o * 32 + i] * G[i];
            const __hip_bfloat16* yc = y_s + c * NHALO_A;
            float a2 = c5b[c];
            #pragma unroll
            for (int t3 = 0; t3 < 3; ++t3)
                #pragma unroll
                for (int t4 = 0; t4 < 3; ++t4)
                    a2 += c5w[c * 9 + t3 * 3 + t4] * bf2f(yc[(py + 1 + t3) * HAW + (px + 1 + t4)]);
            ov[kk][o] = a + a2;
        }
    }

    // ---------- pack to NHWC bf16 (shuffle folded) + stats ----------
    // half h: z[p*128 + h*64 + 2j]   = ov[1][j]  (even cp)
    //         z[p*128 + h*64 + 2j+1] = ov[0][j]  (odd  cp)
    float s = 0.f, ss = 0.f;
    unsigned int pk[32];
    #pragma unroll
    for (int j = 0; j < 32; ++j) {
        const unsigned short lo = f2ubf(ov[1][j]);
        const unsigned short hi = f2ubf(ov[0][j]);
        const float flo = ubf2f(lo), fhi = ubf2f(hi);
        s += flo + fhi; ss += flo * flo + fhi * fhi;
        pk[j] = (unsigned int)lo | ((unsigned int)hi << 16);
    }
    unsigned int* zp = zout + ((size_t)b * HWsz + (size_t)gh * W_ + gw) * 64 + half * 32;
    #pragma unroll
    for (int q = 0; q < 8; ++q)
        *reinterpret_cast<uint4*>(zp + q * 4) =
            make_uint4(pk[4*q], pk[4*q+1], pk[4*q+2], pk[4*q+3]);

    // ---------- LN2 stats ----------
    if (half == 0) { red_s[p] = s; red_ss[p] = ss; }
    __syncthreads();
    if (half == 1) {
        const float S  = red_s[p] + s;
        const float SS = red_ss[p] + ss;
        const float mu  = S * (1.0f / 128.0f);
        const float var = SS * (1.0f / 128.0f) - mu * mu;
        st2[(size_t)b * HWsz + gh * W_ + gw] = make_float2(mu, rsqrtf(var + 1e-6f));
    }
}

// =====================================================================
// Kernel B: LN2 -> dw3 -> GELU (register, lane = (col, chunk))
//           -> 128x128 pointwise via MFMA -> f32 out
// =====================================================================
__global__ __launch_bounds__(256, 4)
void kernelB(const unsigned short* __restrict__ z, const float2* __restrict__ st2,
             const float* __restrict__ n2w, const float* __restrict__ n2b,
             const float* __restrict__ dwT, const float* __restrict__ dwB,
             const float* __restrict__ pwW, const float* __restrict__ pwB,
             float* __restrict__ out)
{
    __shared__ unsigned short g_s[PBH * PBW * GPITCH];   // 34,816 B

    const int tid  = threadIdx.x;
    const int lane = tid & 63;
    const int wv   = tid >> 6;
    const int b    = blockIdx.z;
    const int h0   = blockIdx.y * PBH;
    const int w0   = blockIdx.x * PBW;

    // ---------------- Phase L: LN2 + dw3 + GELU -> g_s (bf16) ----------------
    {
        const int cc = lane & 15;          // channel chunk (8 ch)
        const int sl = lane >> 4;          // 0..3
        const int s  = wv * 4 + sl;        // col in patch 0..15
        const int gx = w0 + s;
        const int cbase = cc * 8;

        float nw[8], nb[8], db[8];
        #pragma unroll
        for (int j = 0; j < 8; ++j) {
            nw[j] = n2w[cbase + j];
            nb[j] = n2b[cbase + j];
            db[j] = dwB[cbase + j];
        }

        for (int r = 0; r < PBH; ++r) {
            const int gy = h0 + r;
            float a[8];
            #pragma unroll
            for (int j = 0; j < 8; ++j) a[j] = db[j];

            #pragma unroll
            for (int dy = -1; dy <= 1; ++dy) {
                const int yy = gy + dy;
                const bool vy = (unsigned)yy < (unsigned)H_;
                const int yc = yy < 0 ? 0 : (yy > H_ - 1 ? H_ - 1 : yy);
                #pragma unroll
                for (int dx = -1; dx <= 1; ++dx) {
                    const int tap = (dy + 1) * 3 + (dx + 1);
                    const int xx = gx + dx;
                    const bool v = vy && ((unsigned)xx < (unsigned)W_);
                    const int xc = xx < 0 ? 0 : (xx > W_ - 1 ? W_ - 1 : xx);
                    const size_t pp = (size_t)b * HWsz + (size_t)yc * W_ + xc;
                    const uint4 zv = *reinterpret_cast<const uint4*>(z + pp * Cch + cbase);
                    const float2 st = st2[pp];
                    const float m = v ? 1.f : 0.f;
                    const unsigned short* zu = reinterpret_cast<const unsigned short*>(&zv);
                    #pragma unroll
                    for (int j = 0; j < 8; ++j) {
                        const float wgt = dwT[tap * Cch + cbase + j] * m;
                        const float zf  = ubf2f(zu[j]);
                        const float t   = (zf - st.x) * st.y;
                        a[j] += wgt * (t * nw[j] + nb[j]);
                    }
                }
            }

            unsigned int pk[4];
            #pragma unroll
            for (int q = 0; q < 4; ++q) {
                const unsigned short lo = f2ubf(gelu_exact(a[2*q]));
                const unsigned short hi = f2ubf(gelu_exact(a[2*q+1]));
                pk[q] = (unsigned int)lo | ((unsigned int)hi << 16);
            }
            const int row = r * PBW + s;
            const int boff = row * (GPITCH * 2) + ((cbase * 2) ^ ((row & 3) << 4));
            *reinterpret_cast<uint4*>(reinterpret_cast<char*>(g_s) + boff) =
                make_uint4(pk[0], pk[1], pk[2], pk[3]);
        }
    }
    __syncthreads();

    // ---------------- Phase P: 128x128 pointwise via MFMA ----------------
    {
        const int ll = lane & 15;
        const int lh = lane >> 4;

        bf16x8 bfr[2][4];
        float  pb[2];
        #pragma unroll
        for (int t2 = 0; t2 < 2; ++t2) {
            const int o = (wv * 2 + t2) * 16 + ll;
            pb[t2] = pwB[o];
            #pragma unroll
            for (int kt = 0; kt < 4; ++kt) {
                const float* wp = pwW + (size_t)o * Cch + kt * 32 + lh * 8;
                bf16x8 vv;
                #pragma unroll
                for (int j = 0; j < 8; ++j) vv[j] = (__bf16)wp[j];
                bfr[t2][kt] = vv;
            }
        }

        #pragma unroll
        for (int r = 0; r < PBH; ++r) {
            const int row = r * PBW + ll;
            bf16x8 af[4];
            #pragma unroll
            for (int kt = 0; kt < 4; ++kt) {
                const int boff = row * (GPITCH * 2) + ((kt * 64 + lh * 16) ^ ((row & 3) << 4));
                af[kt] = *reinterpret_cast<const bf16x8*>(
                            reinterpret_cast<const char*>(g_s) + boff);
            }
            #pragma unroll
            for (int t2 = 0; t2 < 2; ++t2) {
                f32x4 acc = {0.f, 0.f, 0.f, 0.f};
                #pragma unroll
                for (int kt = 0; kt < 4; ++kt)
                    acc = __builtin_amdgcn_mfma_f32_16x16x32_bf16(af[kt], bfr[t2][kt], acc, 0, 0, 0);
                const int o = (wv * 2 + t2) * 16 + ll;
                float4 res = make_float4(acc[0] + pb[t2], acc[1] + pb[t2],
                                         acc[2] + pb[t2], acc[3] + pb[t2]);
                *reinterpret_cast<float4*>(
                    out + ((size_t)b * Cch + o) * HWsz + (size_t)(h0 + r) * W_ + w0 + lh * 4) = res;
            }
        }
    }
}

// =====================================================================
extern "C" void kernel_launch(void* const* d_in, const int* in_sizes, int n_in,
                              void* d_out, int out_size, void* d_ws, size_t ws_size,
                              hipStream_t stream)
{
    const float* x    = (const float*)d_in[0];
    const float* n1w  = (const float*)d_in[1];
    const float* n1b  = (const float*)d_in[2];
    const float* n2w  = (const float*)d_in[3];
    const float* n2b  = (const float*)d_in[4];
    const float* c5w  = (const float*)d_in[5];
    const float* c5b  = (const float*)d_in[6];
    const float* ldww = (const float*)d_in[7];
    const float* ldwb = (const float*)d_in[8];
    const float* lpww = (const float*)d_in[9];
    const float* lpwb = (const float*)d_in[10];
    const float* s1dw = (const float*)d_in[11];
    const float* s1db = (const float*)d_in[12];
    const float* s1pw = (const float*)d_in[13];
    const float* s1pb = (const float*)d_in[14];
    const float* s2dw = (const float*)d_in[15];
    const float* s2db = (const float*)d_in[16];
    const float* s2pw = (const float*)d_in[17];
    const float* s2pb = (const float*)d_in[18];
    const float* s3dw = (const float*)d_in[19];
    const float* s3db = (const float*)d_in[20];
    const float* s3pw = (const float*)d_in[21];
    const float* s3pb = (const float*)d_in[22];
    const float* s4dw = (const float*)d_in[23];
    const float* s4db = (const float*)d_in[24];
    const float* s4pw = (const float*)d_in[25];
    const float* s4pb = (const float*)d_in[26];

    // workspace layout: z (bf16 NHWC) | st1 (float2) | st2 (float2) | dwT
    const size_t zBytes  = (size_t)8 * Cch * HWsz * sizeof(unsigned short); // 102,760,448
    const size_t stBytes = (size_t)8 * HWsz * sizeof(float2);               //   3,211,264
    unsigned int* z_u32 = (unsigned int*)d_ws;
    unsigned short* z_u16 = (unsigned short*)d_ws;
    float2* st1 = (float2*)((char*)d_ws + zBytes);
    float2* st2 = (float2*)((char*)d_ws + zBytes + stBytes);
    float*  dwT = (float*)((char*)d_ws + zBytes + 2 * stBytes);

    prep<<<dim3(5), 256, 0, stream>>>(ldww, dwT);
    ln_stats<<<dim3(HWsz / 256, 8), 256, 0, stream>>>(x, st1);

    kernelA<<<dim3(W_ / TAW, H_ / TAH, 8), 256, 0, stream>>>(
        x, st1, n1w, n1b, c5w, c5b,
        s1dw, s1db, s1pw, s1pb,
        s2dw, s2db, s2pw, s2pb,
        s3dw, s3db, s3pw, s3pb,
        s4dw, s4db, s4pw, s4pb, z_u32, st2);

    kernelB<<<dim3(W_ / PBW, H_ / PBH, 8), 256, 0, stream>>>(
        z_u16, st2, n2w, n2b, dwT, ldwb, lpww, lpwb, (float*)d_out);
}

// Round 6
// 2616.964 us; speedup vs baseline: 1.3576x; 1.3576x over previous
//
#include <hip/hip_runtime.h>
#include <hip/hip_bf16.h>
#include <math.h>

#define H_   224
#define W_   224
#define HWsz 50176      // 224*224
#define Cch  128

// Kernel A: out tile 8x16, halo 2 -> 12x20
#define TAH 8
#define TAW 16
#define HAH 12
#define HAW 20
#define NHALO_A (HAH*HAW)   // 240

// Kernel B: patch 8 rows x 16 cols
#define PBH 8
#define PBW 16
#define GPITCH 136          // g_s row pitch in bf16 units (272 B)

typedef __bf16 bf16x8 __attribute__((ext_vector_type(8)));
typedef float  f32x4  __attribute__((ext_vector_type(4)));

__device__ __forceinline__ float bf2f(__hip_bfloat16 v) { return __bfloat162float(v); }
__device__ __forceinline__ __hip_bfloat16 f2bf(float v) { return __float2bfloat16(v); }
__device__ __forceinline__ float ubf2f(unsigned short u) {
    unsigned x = ((unsigned)u) << 16; return __int_as_float((int)x);
}
__device__ __forceinline__ unsigned short f2ubf(float f) {
    __hip_bfloat16 h = __float2bfloat16(f);
    return *reinterpret_cast<unsigned short*>(&h);
}
__device__ __forceinline__ float gelu_exact(float x) {
    return 0.5f * x * (1.0f + erff(x * 0.70710678118654752440f));
}

// =====================================================================
// prep: transpose ldw depthwise weights to dwT[tap][c]
// =====================================================================
__global__ __launch_bounds__(256)
void prep(const float* __restrict__ ldww, float* __restrict__ dwT)
{
    const int i = blockIdx.x * 256 + threadIdx.x;
    if (i < 9 * Cch) {
        const int t = i >> 7, c = i & 127;
        dwT[i] = ldww[c * 9 + t];
    }
}

// =====================================================================
// ln_stats: per-pixel LN1 statistics (mu, 1/sigma), coalesced
// =====================================================================
__global__ __launch_bounds__(256)
void ln_stats(const float* __restrict__ x, float2* __restrict__ st)
{
    const int sp = blockIdx.x * 256 + threadIdx.x;
    const int b  = blockIdx.y;
    const float* xp = x + (size_t)b * Cch * HWsz + sp;
    float s = 0.f, ss = 0.f;
    #pragma unroll 8
    for (int c = 0; c < Cch; ++c) {
        float v = xp[(size_t)c * HWsz];
        s += v; ss += v * v;
    }
    const float mu  = s * (1.0f / 128.0f);
    const float var = ss * (1.0f / 128.0f) - mu * mu;
    st[(size_t)b * HWsz + sp] = make_float2(mu, rsqrtf(var + 1e-6f));
}

// =====================================================================
// Kernel A: LN1 -> 4 shift branches + c5 -> shuffle -> z (bf16 NHWC)
// + LN2 stats.  Low-live-set variant: G0/G1 only, pack-as-you-go.
// =====================================================================
__global__ __launch_bounds__(256, 2)
void kernelA(const float* __restrict__ x, const float2* __restrict__ st1,
             const float* __restrict__ n1w, const float* __restrict__ n1b,
             const float* __restrict__ c5w, const float* __restrict__ c5b,
             const float* __restrict__ s1dw, const float* __restrict__ s1db,
             const float* __restrict__ s1pw, const float* __restrict__ s1pb,
             const float* __restrict__ s2dw, const float* __restrict__ s2db,
             const float* __restrict__ s2pw, const float* __restrict__ s2pb,
             const float* __restrict__ s3dw, const float* __restrict__ s3db,
             const float* __restrict__ s3pw, const float* __restrict__ s3pb,
             const float* __restrict__ s4dw, const float* __restrict__ s4db,
             const float* __restrict__ s4pw, const float* __restrict__ s4pb,
             unsigned int* __restrict__ zout, float2* __restrict__ st2)
{
    __shared__ __hip_bfloat16 y_s[Cch * NHALO_A];          // 61,440 B
    __shared__ float red_s[TAH * TAW], red_ss[TAH * TAW];  // 1 KB

    const int tid = threadIdx.x;
    const int b   = blockIdx.z;
    const int h0  = blockIdx.y * TAH;
    const int w0  = blockIdx.x * TAW;

    // ---------- Phase 1: single-pass LN1 into y_s ----------
    if (tid < NHALO_A) {
        const int ph = tid / HAW, pw = tid - ph * HAW;
        const int gy = h0 - 2 + ph, gx = w0 - 2 + pw;
        if (gy >= 0 && gy < H_ && gx >= 0 && gx < W_) {
            const float2 st = st1[(size_t)b * HWsz + gy * W_ + gx];
            const float* xp = x + (size_t)b * Cch * HWsz + (size_t)gy * W_ + gx;
            #pragma unroll 8
            for (int c = 0; c < Cch; ++c) {
                float v = xp[(size_t)c * HWsz];
                y_s[c * NHALO_A + tid] = f2bf((v - st.x) * st.y * n1w[c] + n1b[c]);
            }
        } else {
            for (int c = 0; c < Cch; ++c) y_s[c * NHALO_A + tid] = f2bf(0.f);
        }
    }
    __syncthreads();

    // ---------- Phase 2: (pixel x chunk-half), wave-uniform half ----------
    const int lane = tid & 63;
    const int wv   = tid >> 6;
    const int half = wv >> 1;
    const int p    = ((wv & 1) << 6) | lane;   // 0..127
    const int py   = p >> 4, px = p & 15;
    const int gh   = h0 + py, gw = w0 + px;

    bool rowOK[3], colOK[3];
    #pragma unroll
    for (int t = 0; t < 3; ++t) {
        rowOK[t] = (gh - 1 + t >= 0) && (gh - 1 + t < H_);
        colOK[t] = (gw - 1 + t >= 0) && (gw - 1 + t < W_);
    }

    // chunk table: k=0:s1 sh(1,1) ob 64 | k=1:s2 sh(-1,1) ob 0
    //              k=2:s3 sh(-1,-1) ob 96 | k=3:s4 sh(1,-1) ob 32
    // half h uses k0=2h (-> odd cp, hi) and k1=2h+1 (-> even cp, lo)
    const int k0 = half * 2, k1 = half * 2 + 1;
    const float* dwW0 = (k0 == 0) ? s1dw : s3dw;
    const float* dwB0 = (k0 == 0) ? s1db : s3db;
    const float* pwW0 = (k0 == 0) ? s1pw : s3pw;
    const float* pwB0 = (k0 == 0) ? s1pb : s3pb;
    const float* dwW1 = (k1 == 1) ? s2dw : s4dw;
    const float* dwB1 = (k1 == 1) ? s2db : s4db;
    const float* pwW1 = (k1 == 1) ? s2pw : s4pw;
    const float* pwB1 = (k1 == 1) ? s2pb : s4pb;
    const int shh0 = (half == 0) ? 1 : -1, shw0 = (half == 0) ? 1 : -1;
    const int shh1 = (half == 0) ? -1 : 1, shw1 = (half == 0) ? 1 : -1;
    const int ob0  = (half == 0) ? 64 : 96;
    const int ob1  = (half == 0) ? 0  : 32;

    float G0[32], G1[32];

    #define COMPUTE_G(Garr, kBase, dwW, dwB, shh, shw)                              \
    {                                                                               \
        const int rb = py + 1 - (shh);                                              \
        const int cb = px + 1 - (shw);                                              \
        _Pragma("unroll")                                                           \
        for (int i = 0; i < 32; ++i) {                                              \
            const __hip_bfloat16* yc = y_s + ((kBase) * 32 + i) * NHALO_A;          \
            float a = dwB[i];                                                       \
            _Pragma("unroll")                                                       \
            for (int t3 = 0; t3 < 3; ++t3)                                          \
                _Pragma("unroll")                                                   \
                for (int t4 = 0; t4 < 3; ++t4) {                                    \
                    float v = (rowOK[t3] && colOK[t4])                              \
                            ? bf2f(yc[(rb + t3) * HAW + (cb + t4)]) : 0.f;          \
                    a += dwW[i * 9 + t3 * 3 + t4] * v;                              \
                }                                                                   \
            Garr[i] = gelu_exact(a);                                                \
        }                                                                           \
    }

    COMPUTE_G(G0, k0, dwW0, dwB0, shh0, shw0)
    COMPUTE_G(G1, k1, dwW1, dwB1, shh1, shw1)
    #undef COMPUTE_G

    // ---------- pack to NHWC bf16 (shuffle folded) + stats, as-you-go ----------
    float s = 0.f, ss = 0.f;
    unsigned int* zp = zout + ((size_t)b * HWsz + (size_t)gh * W_ + gw) * 64 + half * 32;

    for (int q = 0; q < 8; ++q) {
        unsigned int pk[4];
        #pragma unroll
        for (int t = 0; t < 4; ++t) {
            const int j = 4 * q + t;
            // pointwise dots (two independent chains)
            float vhi = pwB0[j], vlo = pwB1[j];
            #pragma unroll
            for (int i = 0; i < 32; ++i) {
                vhi += pwW0[j * 32 + i] * G0[i];
                vlo += pwW1[j * 32 + i] * G1[i];
            }
            // c5 depthwise on channels c0 (hi) and c1 (lo)
            const int c0 = ob0 + j, c1 = ob1 + j;
            const __hip_bfloat16* yc0 = y_s + c0 * NHALO_A;
            const __hip_bfloat16* yc1 = y_s + c1 * NHALO_A;
            float a0 = c5b[c0], a1 = c5b[c1];
            #pragma unroll
            for (int t3 = 0; t3 < 3; ++t3)
                #pragma unroll
                for (int t4 = 0; t4 < 3; ++t4) {
                    const int off = (py + 1 + t3) * HAW + (px + 1 + t4);
                    a0 += c5w[c0 * 9 + t3 * 3 + t4] * bf2f(yc0[off]);
                    a1 += c5w[c1 * 9 + t3 * 3 + t4] * bf2f(yc1[off]);
                }
            vhi += a0; vlo += a1;
            const unsigned short lo = f2ubf(vlo);
            const unsigned short hi = f2ubf(vhi);
            const float flo = ubf2f(lo), fhi = ubf2f(hi);
            s += flo + fhi; ss += flo * flo + fhi * fhi;
            pk[t] = (unsigned int)lo | ((unsigned int)hi << 16);
        }
        *reinterpret_cast<uint4*>(zp + q * 4) = make_uint4(pk[0], pk[1], pk[2], pk[3]);
    }

    // ---------- LN2 stats ----------
    if (half == 0) { red_s[p] = s; red_ss[p] = ss; }
    __syncthreads();
    if (half == 1) {
        const float S  = red_s[p] + s;
        const float SS = red_ss[p] + ss;
        const float mu  = S * (1.0f / 128.0f);
        const float var = SS * (1.0f / 128.0f) - mu * mu;
        st2[(size_t)b * HWsz + gh * W_ + gw] = make_float2(mu, rsqrtf(var + 1e-6f));
    }
}

// =====================================================================
// Kernel B: LN2 -> dw3 -> GELU (register, lane = (col, chunk))
//           -> 128x128 pointwise via MFMA -> f32 out
// =====================================================================
__global__ __launch_bounds__(256, 4)
void kernelB(const unsigned short* __restrict__ z, const float2* __restrict__ st2,
             const float* __restrict__ n2w, const float* __restrict__ n2b,
             const float* __restrict__ dwT, const float* __restrict__ dwB,
             const float* __restrict__ pwW, const float* __restrict__ pwB,
             float* __restrict__ out)
{
    __shared__ unsigned short g_s[PBH * PBW * GPITCH];   // 34,816 B

    const int tid  = threadIdx.x;
    const int lane = tid & 63;
    const int wv   = tid >> 6;
    const int b    = blockIdx.z;
    const int h0   = blockIdx.y * PBH;
    const int w0   = blockIdx.x * PBW;

    // ---------------- Phase L: LN2 + dw3 + GELU -> g_s (bf16) ----------------
    {
        const int cc = lane & 15;          // channel chunk (8 ch)
        const int sl = lane >> 4;          // 0..3
        const int s  = wv * 4 + sl;        // col in patch 0..15
        const int gx = w0 + s;
        const int cbase = cc * 8;

        float nw[8], nb[8], db[8];
        #pragma unroll
        for (int j = 0; j < 8; ++j) {
            nw[j] = n2w[cbase + j];
            nb[j] = n2b[cbase + j];
            db[j] = dwB[cbase + j];
        }

        for (int r = 0; r < PBH; ++r) {
            const int gy = h0 + r;
            float a[8];
            #pragma unroll
            for (int j = 0; j < 8; ++j) a[j] = db[j];

            #pragma unroll
            for (int dy = -1; dy <= 1; ++dy) {
                const int yy = gy + dy;
                const bool vy = (unsigned)yy < (unsigned)H_;
                const int yc = yy < 0 ? 0 : (yy > H_ - 1 ? H_ - 1 : yy);
                #pragma unroll
                for (int dx = -1; dx <= 1; ++dx) {
                    const int tap = (dy + 1) * 3 + (dx + 1);
                    const int xx = gx + dx;
                    const bool v = vy && ((unsigned)xx < (unsigned)W_);
                    const int xc = xx < 0 ? 0 : (xx > W_ - 1 ? W_ - 1 : xx);
                    const size_t pp = (size_t)b * HWsz + (size_t)yc * W_ + xc;
                    const uint4 zv = *reinterpret_cast<const uint4*>(z + pp * Cch + cbase);
                    const float2 st = st2[pp];
                    const float m = v ? 1.f : 0.f;
                    const unsigned short* zu = reinterpret_cast<const unsigned short*>(&zv);
                    #pragma unroll
                    for (int j = 0; j < 8; ++j) {
                        const float wgt = dwT[tap * Cch + cbase + j] * m;
                        const float zf  = ubf2f(zu[j]);
                        const float t   = (zf - st.x) * st.y;
                        a[j] += wgt * (t * nw[j] + nb[j]);
                    }
                }
            }

            unsigned int pk[4];
            #pragma unroll
            for (int q = 0; q < 4; ++q) {
                const unsigned short lo = f2ubf(gelu_exact(a[2*q]));
                const unsigned short hi = f2ubf(gelu_exact(a[2*q+1]));
                pk[q] = (unsigned int)lo | ((unsigned int)hi << 16);
            }
            const int row = r * PBW + s;
            const int boff = row * (GPITCH * 2) + ((cbase * 2) ^ ((row & 3) << 4));
            *reinterpret_cast<uint4*>(reinterpret_cast<char*>(g_s) + boff) =
                make_uint4(pk[0], pk[1], pk[2], pk[3]);
        }
    }
    __syncthreads();

    // ---------------- Phase P: 128x128 pointwise via MFMA ----------------
    {
        const int ll = lane & 15;
        const int lh = lane >> 4;

        bf16x8 bfr[2][4];
        float  pb[2];
        #pragma unroll
        for (int t2 = 0; t2 < 2; ++t2) {
            const int o = (wv * 2 + t2) * 16 + ll;
            pb[t2] = pwB[o];
            #pragma unroll
            for (int kt = 0; kt < 4; ++kt) {
                const float* wp = pwW + (size_t)o * Cch + kt * 32 + lh * 8;
                bf16x8 vv;
                #pragma unroll
                for (int j = 0; j < 8; ++j) vv[j] = (__bf16)wp[j];
                bfr[t2][kt] = vv;
            }
        }

        #pragma unroll
        for (int r = 0; r < PBH; ++r) {
            const int row = r * PBW + ll;
            bf16x8 af[4];
            #pragma unroll
            for (int kt = 0; kt < 4; ++kt) {
                const int boff = row * (GPITCH * 2) + ((kt * 64 + lh * 16) ^ ((row & 3) << 4));
                af[kt] = *reinterpret_cast<const bf16x8*>(
                            reinterpret_cast<const char*>(g_s) + boff);
            }
            #pragma unroll
            for (int t2 = 0; t2 < 2; ++t2) {
                f32x4 acc = {0.f, 0.f, 0.f, 0.f};
                #pragma unroll
                for (int kt = 0; kt < 4; ++kt)
                    acc = __builtin_amdgcn_mfma_f32_16x16x32_bf16(af[kt], bfr[t2][kt], acc, 0, 0, 0);
                const int o = (wv * 2 + t2) * 16 + ll;
                float4 res = make_float4(acc[0] + pb[t2], acc[1] + pb[t2],
                                         acc[2] + pb[t2], acc[3] + pb[t2]);
                *reinterpret_cast<float4*>(
                    out + ((size_t)b * Cch + o) * HWsz + (size_t)(h0 + r) * W_ + w0 + lh * 4) = res;
            }
        }
    }
}

// =====================================================================
extern "C" void kernel_launch(void* const* d_in, const int* in_sizes, int n_in,
                              void* d_out, int out_size, void* d_ws, size_t ws_size,
                              hipStream_t stream)
{
    const float* x    = (const float*)d_in[0];
    const float* n1w  = (const float*)d_in[1];
    const float* n1b  = (const float*)d_in[2];
    const float* n2w  = (const float*)d_in[3];
    const float* n2b  = (const float*)d_in[4];
    const float* c5w  = (const float*)d_in[5];
    const float* c5b  = (const float*)d_in[6];
    const float* ldww = (const float*)d_in[7];
    const float* ldwb = (const float*)d_in[8];
    const float* lpww = (const float*)d_in[9];
    const float* lpwb = (const float*)d_in[10];
    const float* s1dw = (const float*)d_in[11];
    const float* s1db = (const float*)d_in[12];
    const float* s1pw = (const float*)d_in[13];
    const float* s1pb = (const float*)d_in[14];
    const float* s2dw = (const float*)d_in[15];
    const float* s2db = (const float*)d_in[16];
    const float* s2pw = (const float*)d_in[17];
    const float* s2pb = (const float*)d_in[18];
    const float* s3dw = (const float*)d_in[19];
    const float* s3db = (const float*)d_in[20];
    const float* s3pw = (const float*)d_in[21];
    const float* s3pb = (const float*)d_in[22];
    const float* s4dw = (const float*)d_in[23];
    const float* s4db = (const float*)d_in[24];
    const float* s4pw = (const float*)d_in[25];
    const float* s4pb = (const float*)d_in[26];

    // workspace layout: z (bf16 NHWC) | st1 (float2) | st2 (float2) | dwT
    const size_t zBytes  = (size_t)8 * Cch * HWsz * sizeof(unsigned short); // 102,760,448
    const size_t stBytes = (size_t)8 * HWsz * sizeof(float2);               //   3,211,264
    unsigned int* z_u32 = (unsigned int*)d_ws;
    unsigned short* z_u16 = (unsigned short*)d_ws;
    float2* st1 = (float2*)((char*)d_ws + zBytes);
    float2* st2 = (float2*)((char*)d_ws + zBytes + stBytes);
    float*  dwT = (float*)((char*)d_ws + zBytes + 2 * stBytes);

    prep<<<dim3(5), 256, 0, stream>>>(ldww, dwT);
    ln_stats<<<dim3(HWsz / 256, 8), 256, 0, stream>>>(x, st1);

    kernelA<<<dim3(W_ / TAW, H_ / TAH, 8), 256, 0, stream>>>(
        x, st1, n1w, n1b, c5w, c5b,
        s1dw, s1db, s1pw, s1pb,
        s2dw, s2db, s2pw, s2pb,
        s3dw, s3db, s3pw, s3pb,
        s4dw, s4db, s4pw, s4pb, z_u32, st2);

    kernelB<<<dim3(W_ / PBW, H_ / PBH, 8), 256, 0, stream>>>(
        z_u16, st2, n2w, n2b, dwT, ldwb, lpww, lpwb, (float*)d_out);
}

// Round 7
// 1386.162 us; speedup vs baseline: 2.5630x; 1.8879x over previous
//
#include <hip/hip_runtime.h>
#include <hip/hip_bf16.h>
#include <math.h>

#define H_   224
#define W_   224
#define HWsz 50176      // 224*224
#define Cch  128

// Kernel A: out tile 8x16, halo 2 -> 12x20
#define TAH 8
#define TAW 16
#define HAH 12
#define HAW 20
#define NHALO_A (HAH*HAW)   // 240
#define RSA 241             // y_s padded row length (pixels) -> 482 B/row

// Kernel B: patch 8 rows x 16 cols
#define PBH 8
#define PBW 16
#define GPITCH 136          // g_s row pitch in bf16 units (272 B)

// lnT: pixels per block
#define TPX 64

typedef __bf16 bf16x8 __attribute__((ext_vector_type(8)));
typedef float  f32x4  __attribute__((ext_vector_type(4)));

__device__ __forceinline__ float bf2f(__hip_bfloat16 v) { return __bfloat162float(v); }
__device__ __forceinline__ __hip_bfloat16 f2bf(float v) { return __float2bfloat16(v); }
__device__ __forceinline__ float ubf2f(unsigned short u) {
    unsigned x = ((unsigned)u) << 16; return __int_as_float((int)x);
}
__device__ __forceinline__ unsigned short f2ubf(float f) {
    __hip_bfloat16 h = __float2bfloat16(f);
    return *reinterpret_cast<unsigned short*>(&h);
}
__device__ __forceinline__ float gelu_exact(float x) {
    return 0.5f * x * (1.0f + erff(x * 0.70710678118654752440f));
}

// =====================================================================
// prep: transpose ldw depthwise weights to dwT[tap][c]
// =====================================================================
__global__ __launch_bounds__(256)
void prep(const float* __restrict__ ldww, float* __restrict__ dwT)
{
    const int i = blockIdx.x * 256 + threadIdx.x;
    if (i < 9 * Cch) {
        const int t = i >> 7, c = i & 127;
        dwT[i] = ldww[c * 9 + t];
    }
}

// =====================================================================
// lnT: LN1 (stats + normalize) + NCHW->NHWC transpose, bf16 out
// block: 64 pixels x 128 channels
// =====================================================================
__global__ __launch_bounds__(256, 4)
void lnT(const float* __restrict__ x,
         const float* __restrict__ n1w, const float* __restrict__ n1b,
         unsigned int* __restrict__ y)
{
    __shared__ float xs[TPX][Cch + 1];      // 33,024 B
    __shared__ float rs_[4][TPX], rss_[4][TPX];
    __shared__ float2 st_s[TPX];

    const int t   = threadIdx.x;
    const int b   = blockIdx.y;
    const int sp0 = blockIdx.x * TPX;

    // phase a: coalesced load, transpose into LDS
    {
        const int lane = t & 63, wv = t >> 6;
        const float* xb = x + (size_t)b * Cch * HWsz + sp0 + lane;
        #pragma unroll 8
        for (int k = 0; k < 32; ++k) {
            const int c = wv * 32 + k;
            xs[lane][c] = xb[(size_t)c * HWsz];
        }
    }
    __syncthreads();

    // phase b: per-pixel stats (4 threads per pixel)
    {
        const int p = t & 63, q = t >> 6;
        float s = 0.f, ss = 0.f;
        #pragma unroll
        for (int k = 0; k < 32; ++k) {
            const float v = xs[p][q * 32 + k];
            s += v; ss += v * v;
        }
        rs_[q][p] = s; rss_[q][p] = ss;
    }
    __syncthreads();
    if (t < TPX) {
        const float S  = rs_[0][t] + rs_[1][t] + rs_[2][t] + rs_[3][t];
        const float SS = rss_[0][t] + rss_[1][t] + rss_[2][t] + rss_[3][t];
        const float mu  = S * (1.0f / 128.0f);
        const float var = SS * (1.0f / 128.0f) - mu * mu;
        st_s[t] = make_float2(mu, rsqrtf(var + 1e-6f));
    }
    __syncthreads();

    // phase c: normalize + pack bf16 + coalesced NHWC store
    {
        const int ch = t & 15;          // 16B chunk (8 channels)
        const int pb = t >> 4;          // 0..15
        float w8[8], b8[8];
        #pragma unroll
        for (int j = 0; j < 8; ++j) {
            w8[j] = n1w[ch * 8 + j];
            b8[j] = n1b[ch * 8 + j];
        }
        #pragma unroll
        for (int it = 0; it < 4; ++it) {
            const int p = it * 16 + pb;
            const float2 st = st_s[p];
            unsigned int pk[4];
            #pragma unroll
            for (int u = 0; u < 4; ++u) {
                const int c0 = ch * 8 + u * 2;
                const float v0 = (xs[p][c0]     - st.x) * st.y * w8[u*2]   + b8[u*2];
                const float v1 = (xs[p][c0 + 1] - st.x) * st.y * w8[u*2+1] + b8[u*2+1];
                pk[u] = (unsigned int)f2ubf(v0) | ((unsigned int)f2ubf(v1) << 16);
            }
            *reinterpret_cast<uint4*>(y + ((size_t)b * HWsz + sp0 + p) * 64 + ch * 4) =
                make_uint4(pk[0], pk[1], pk[2], pk[3]);
        }
    }
}

// =====================================================================
// Kernel A: y(NHWC bf16) -> 4 shift branches + c5 -> shuffle -> z (bf16 NHWC)
// + LN2 stats
// =====================================================================
__global__ __launch_bounds__(256)
void kernelA(const unsigned short* __restrict__ y,
             const float* __restrict__ c5w, const float* __restrict__ c5b,
             const float* __restrict__ s1dw, const float* __restrict__ s1db,
             const float* __restrict__ s1pw, const float* __restrict__ s1pb,
             const float* __restrict__ s2dw, const float* __restrict__ s2db,
             const float* __restrict__ s2pw, const float* __restrict__ s2pb,
             const float* __restrict__ s3dw, const float* __restrict__ s3db,
             const float* __restrict__ s3pw, const float* __restrict__ s3pb,
             const float* __restrict__ s4dw, const float* __restrict__ s4db,
             const float* __restrict__ s4pw, const float* __restrict__ s4pb,
             unsigned int* __restrict__ zout, float2* __restrict__ st2)
{
    __shared__ __hip_bfloat16 y_s[Cch * RSA];              // 61,696 B
    __shared__ float red_s[TAH * TAW], red_ss[TAH * TAW];  // 1 KB

    const int tid = threadIdx.x;
    const int b   = blockIdx.z;
    const int h0  = blockIdx.y * TAH;
    const int w0  = blockIdx.x * TAW;

    // ---------- Phase 1: coalesced NHWC load -> transposed LDS scatter ----------
    {
        const int ch = tid & 15;          // 16B chunk (8 channels)
        const int pb = tid >> 4;          // 0..15
        #pragma unroll
        for (int it = 0; it < 15; ++it) {
            const int p  = it * 16 + pb;  // halo pixel index 0..239
            const int ph = p / HAW, pw2 = p - ph * HAW;
            const int gy = h0 - 2 + ph, gx = w0 - 2 + pw2;
            unsigned int v[4] = {0u, 0u, 0u, 0u};
            if ((unsigned)gy < (unsigned)H_ && (unsigned)gx < (unsigned)W_) {
                const uint4 zv = *reinterpret_cast<const uint4*>(
                    y + ((size_t)b * HWsz + (size_t)gy * W_ + gx) * Cch + ch * 8);
                v[0] = zv.x; v[1] = zv.y; v[2] = zv.z; v[3] = zv.w;
            }
            const unsigned short* vu = reinterpret_cast<const unsigned short*>(v);
            #pragma unroll
            for (int j = 0; j < 8; ++j)
                y_s[(ch * 8 + j) * RSA + p] =
                    *reinterpret_cast<const __hip_bfloat16*>(&vu[j]);
        }
    }
    __syncthreads();

    // ---------- Phase 2: (pixel x chunk-half), wave-uniform half ----------
    const int lane = tid & 63;
    const int wv   = tid >> 6;
    const int half = wv >> 1;
    const int p    = ((wv & 1) << 6) | lane;   // 0..127
    const int py   = p >> 4, px = p & 15;
    const int gh   = h0 + py, gw = w0 + px;

    bool rowOK[3], colOK[3];
    #pragma unroll
    for (int t = 0; t < 3; ++t) {
        rowOK[t] = (gh - 1 + t >= 0) && (gh - 1 + t < H_);
        colOK[t] = (gw - 1 + t >= 0) && (gw - 1 + t < W_);
    }

    // chunk table: k=0:s1 sh(1,1) ob 64 | k=1:s2 sh(-1,1) ob 0
    //              k=2:s3 sh(-1,-1) ob 96 | k=3:s4 sh(1,-1) ob 32
    const int k0 = half * 2, k1 = half * 2 + 1;
    const float* dwW0 = (k0 == 0) ? s1dw : s3dw;
    const float* dwB0 = (k0 == 0) ? s1db : s3db;
    const float* pwW0 = (k0 == 0) ? s1pw : s3pw;
    const float* pwB0 = (k0 == 0) ? s1pb : s3pb;
    const float* dwW1 = (k1 == 1) ? s2dw : s4dw;
    const float* dwB1 = (k1 == 1) ? s2db : s4db;
    const float* pwW1 = (k1 == 1) ? s2pw : s4pw;
    const float* pwB1 = (k1 == 1) ? s2pb : s4pb;
    const int shh0 = (half == 0) ? 1 : -1, shw0 = (half == 0) ? 1 : -1;
    const int shh1 = (half == 0) ? -1 : 1, shw1 = (half == 0) ? 1 : -1;
    const int ob0  = (half == 0) ? 64 : 96;
    const int ob1  = (half == 0) ? 0  : 32;

    float G0[32], G1[32];

    #define COMPUTE_G(Garr, kBase, dwW, dwB, shh, shw)                              \
    {                                                                               \
        const int rb = py + 1 - (shh);                                              \
        const int cb = px + 1 - (shw);                                              \
        _Pragma("unroll")                                                           \
        for (int i = 0; i < 32; ++i) {                                              \
            const __hip_bfloat16* yc = y_s + ((kBase) * 32 + i) * RSA;              \
            float a = dwB[i];                                                       \
            _Pragma("unroll")                                                       \
            for (int t3 = 0; t3 < 3; ++t3)                                          \
                _Pragma("unroll")                                                   \
                for (int t4 = 0; t4 < 3; ++t4) {                                    \
                    float v = (rowOK[t3] && colOK[t4])                              \
                            ? bf2f(yc[(rb + t3) * HAW + (cb + t4)]) : 0.f;          \
                    a += dwW[i * 9 + t3 * 3 + t4] * v;                              \
                }                                                                   \
            Garr[i] = gelu_exact(a);                                                \
        }                                                                           \
    }

    COMPUTE_G(G0, k0, dwW0, dwB0, shh0, shw0)
    COMPUTE_G(G1, k1, dwW1, dwB1, shh1, shw1)
    #undef COMPUTE_G

    // ---------- pack to NHWC bf16 (shuffle folded) + stats, as-you-go ----------
    float s = 0.f, ss = 0.f;
    unsigned int* zp = zout + ((size_t)b * HWsz + (size_t)gh * W_ + gw) * 64 + half * 32;

    for (int q = 0; q < 8; ++q) {
        unsigned int pk[4];
        #pragma unroll
        for (int t = 0; t < 4; ++t) {
            const int j = 4 * q + t;
            float vhi = pwB0[j], vlo = pwB1[j];
            #pragma unroll
            for (int i = 0; i < 32; ++i) {
                vhi += pwW0[j * 32 + i] * G0[i];
                vlo += pwW1[j * 32 + i] * G1[i];
            }
            const int c0 = ob0 + j, c1 = ob1 + j;
            const __hip_bfloat16* yc0 = y_s + c0 * RSA;
            const __hip_bfloat16* yc1 = y_s + c1 * RSA;
            float a0 = c5b[c0], a1 = c5b[c1];
            #pragma unroll
            for (int t3 = 0; t3 < 3; ++t3)
                #pragma unroll
                for (int t4 = 0; t4 < 3; ++t4) {
                    const int off = (py + 1 + t3) * HAW + (px + 1 + t4);
                    a0 += c5w[c0 * 9 + t3 * 3 + t4] * bf2f(yc0[off]);
                    a1 += c5w[c1 * 9 + t3 * 3 + t4] * bf2f(yc1[off]);
                }
            vhi += a0; vlo += a1;
            const unsigned short lo = f2ubf(vlo);
            const unsigned short hi = f2ubf(vhi);
            const float flo = ubf2f(lo), fhi = ubf2f(hi);
            s += flo + fhi; ss += flo * flo + fhi * fhi;
            pk[t] = (unsigned int)lo | ((unsigned int)hi << 16);
        }
        *reinterpret_cast<uint4*>(zp + q * 4) = make_uint4(pk[0], pk[1], pk[2], pk[3]);
    }

    // ---------- LN2 stats ----------
    if (half == 0) { red_s[p] = s; red_ss[p] = ss; }
    __syncthreads();
    if (half == 1) {
        const float S  = red_s[p] + s;
        const float SS = red_ss[p] + ss;
        const float mu  = S * (1.0f / 128.0f);
        const float var = SS * (1.0f / 128.0f) - mu * mu;
        st2[(size_t)b * HWsz + gh * W_ + gw] = make_float2(mu, rsqrtf(var + 1e-6f));
    }
}

// =====================================================================
// Kernel B: LN2 -> dw3 -> GELU (register, lane = (col, chunk))
//           -> 128x128 pointwise via MFMA -> f32 out
// =====================================================================
__global__ __launch_bounds__(256, 4)
void kernelB(const unsigned short* __restrict__ z, const float2* __restrict__ st2,
             const float* __restrict__ n2w, const float* __restrict__ n2b,
             const float* __restrict__ dwT, const float* __restrict__ dwB,
             const float* __restrict__ pwW, const float* __restrict__ pwB,
             float* __restrict__ out)
{
    __shared__ unsigned short g_s[PBH * PBW * GPITCH];   // 34,816 B

    const int tid  = threadIdx.x;
    const int lane = tid & 63;
    const int wv   = tid >> 6;
    const int b    = blockIdx.z;
    const int h0   = blockIdx.y * PBH;
    const int w0   = blockIdx.x * PBW;

    // ---------------- Phase L: LN2 + dw3 + GELU -> g_s (bf16) ----------------
    {
        const int cc = lane & 15;          // channel chunk (8 ch)
        const int sl = lane >> 4;          // 0..3
        const int s  = wv * 4 + sl;        // col in patch 0..15
        const int gx = w0 + s;
        const int cbase = cc * 8;

        float nw[8], nb[8], db[8];
        #pragma unroll
        for (int j = 0; j < 8; ++j) {
            nw[j] = n2w[cbase + j];
            nb[j] = n2b[cbase + j];
            db[j] = dwB[cbase + j];
        }

        for (int r = 0; r < PBH; ++r) {
            const int gy = h0 + r;
            float a[8];
            #pragma unroll
            for (int j = 0; j < 8; ++j) a[j] = db[j];

            #pragma unroll
            for (int dy = -1; dy <= 1; ++dy) {
                const int yy = gy + dy;
                const bool vy = (unsigned)yy < (unsigned)H_;
                const int yc = yy < 0 ? 0 : (yy > H_ - 1 ? H_ - 1 : yy);
                #pragma unroll
                for (int dx = -1; dx <= 1; ++dx) {
                    const int tap = (dy + 1) * 3 + (dx + 1);
                    const int xx = gx + dx;
                    const bool v = vy && ((unsigned)xx < (unsigned)W_);
                    const int xc = xx < 0 ? 0 : (xx > W_ - 1 ? W_ - 1 : xx);
                    const size_t pp = (size_t)b * HWsz + (size_t)yc * W_ + xc;
                    const uint4 zv = *reinterpret_cast<const uint4*>(z + pp * Cch + cbase);
                    const float2 st = st2[pp];
                    const float m = v ? 1.f : 0.f;
                    const unsigned short* zu = reinterpret_cast<const unsigned short*>(&zv);
                    #pragma unroll
                    for (int j = 0; j < 8; ++j) {
                        const float wgt = dwT[tap * Cch + cbase + j] * m;
                        const float zf  = ubf2f(zu[j]);
                        const float t   = (zf - st.x) * st.y;
                        a[j] += wgt * (t * nw[j] + nb[j]);
                    }
                }
            }

            unsigned int pk[4];
            #pragma unroll
            for (int q = 0; q < 4; ++q) {
                const unsigned short lo = f2ubf(gelu_exact(a[2*q]));
                const unsigned short hi = f2ubf(gelu_exact(a[2*q+1]));
                pk[q] = (unsigned int)lo | ((unsigned int)hi << 16);
            }
            const int row = r * PBW + s;
            const int boff = row * (GPITCH * 2) + ((cbase * 2) ^ ((row & 3) << 4));
            *reinterpret_cast<uint4*>(reinterpret_cast<char*>(g_s) + boff) =
                make_uint4(pk[0], pk[1], pk[2], pk[3]);
        }
    }
    __syncthreads();

    // ---------------- Phase P: 128x128 pointwise via MFMA ----------------
    {
        const int ll = lane & 15;
        const int lh = lane >> 4;

        bf16x8 bfr[2][4];
        float  pb[2];
        #pragma unroll
        for (int t2 = 0; t2 < 2; ++t2) {
            const int o = (wv * 2 + t2) * 16 + ll;
            pb[t2] = pwB[o];
            #pragma unroll
            for (int kt = 0; kt < 4; ++kt) {
                const float* wp = pwW + (size_t)o * Cch + kt * 32 + lh * 8;
                bf16x8 vv;
                #pragma unroll
                for (int j = 0; j < 8; ++j) vv[j] = (__bf16)wp[j];
                bfr[t2][kt] = vv;
            }
        }

        #pragma unroll
        for (int r = 0; r < PBH; ++r) {
            const int row = r * PBW + ll;
            bf16x8 af[4];
            #pragma unroll
            for (int kt = 0; kt < 4; ++kt) {
                const int boff = row * (GPITCH * 2) + ((kt * 64 + lh * 16) ^ ((row & 3) << 4));
                af[kt] = *reinterpret_cast<const bf16x8*>(
                            reinterpret_cast<const char*>(g_s) + boff);
            }
            #pragma unroll
            for (int t2 = 0; t2 < 2; ++t2) {
                f32x4 acc = {0.f, 0.f, 0.f, 0.f};
                #pragma unroll
                for (int kt = 0; kt < 4; ++kt)
                    acc = __builtin_amdgcn_mfma_f32_16x16x32_bf16(af[kt], bfr[t2][kt], acc, 0, 0, 0);
                const int o = (wv * 2 + t2) * 16 + ll;
                float4 res = make_float4(acc[0] + pb[t2], acc[1] + pb[t2],
                                         acc[2] + pb[t2], acc[3] + pb[t2]);
                *reinterpret_cast<float4*>(
                    out + ((size_t)b * Cch + o) * HWsz + (size_t)(h0 + r) * W_ + w0 + lh * 4) = res;
            }
        }
    }
}

// =====================================================================
extern "C" void kernel_launch(void* const* d_in, const int* in_sizes, int n_in,
                              void* d_out, int out_size, void* d_ws, size_t ws_size,
                              hipStream_t stream)
{
    const float* x    = (const float*)d_in[0];
    const float* n1w  = (const float*)d_in[1];
    const float* n1b  = (const float*)d_in[2];
    const float* n2w  = (const float*)d_in[3];
    const float* n2b  = (const float*)d_in[4];
    const float* c5w  = (const float*)d_in[5];
    const float* c5b  = (const float*)d_in[6];
    const float* ldww = (const float*)d_in[7];
    const float* ldwb = (const float*)d_in[8];
    const float* lpww = (const float*)d_in[9];
    const float* lpwb = (const float*)d_in[10];
    const float* s1dw = (const float*)d_in[11];
    const float* s1db = (const float*)d_in[12];
    const float* s1pw = (const float*)d_in[13];
    const float* s1pb = (const float*)d_in[14];
    const float* s2dw = (const float*)d_in[15];
    const float* s2db = (const float*)d_in[16];
    const float* s2pw = (const float*)d_in[17];
    const float* s2pb = (const float*)d_in[18];
    const float* s3dw = (const float*)d_in[19];
    const float* s3db = (const float*)d_in[20];
    const float* s3pw = (const float*)d_in[21];
    const float* s3pb = (const float*)d_in[22];
    const float* s4dw = (const float*)d_in[23];
    const float* s4db = (const float*)d_in[24];
    const float* s4pw = (const float*)d_in[25];
    const float* s4pb = (const float*)d_in[26];

    // workspace layout: y (bf16 NHWC) | z (bf16 NHWC) | st2 (float2) | dwT
    const size_t yBytes  = (size_t)8 * Cch * HWsz * sizeof(unsigned short); // 102,760,448
    const size_t zBytes  = yBytes;                                          // 102,760,448
    const size_t stBytes = (size_t)8 * HWsz * sizeof(float2);               //   3,211,264
    unsigned int*   y_u32 = (unsigned int*)d_ws;
    unsigned short* y_u16 = (unsigned short*)d_ws;
    unsigned int*   z_u32 = (unsigned int*)((char*)d_ws + yBytes);
    unsigned short* z_u16 = (unsigned short*)((char*)d_ws + yBytes);
    float2* st2 = (float2*)((char*)d_ws + yBytes + zBytes);
    float*  dwT = (float*)((char*)d_ws + yBytes + zBytes + stBytes);

    prep<<<dim3(5), 256, 0, stream>>>(ldww, dwT);
    lnT<<<dim3(HWsz / TPX, 8), 256, 0, stream>>>(x, n1w, n1b, y_u32);

    kernelA<<<dim3(W_ / TAW, H_ / TAH, 8), 256, 0, stream>>>(
        y_u16, c5w, c5b,
        s1dw, s1db, s1pw, s1pb,
        s2dw, s2db, s2pw, s2pb,
        s3dw, s3db, s3pw, s3pb,
        s4dw, s4db, s4pw, s4pb, z_u32, st2);

    kernelB<<<dim3(W_ / PBW, H_ / PBH, 8), 256, 0, stream>>>(
        z_u16, st2, n2w, n2b, dwT, ldwb, lpww, lpwb, (float*)d_out);
}